// Round 11
// baseline (422.075 us; speedup 1.0000x reference)
//
#include <hip/hip_runtime.h>
#include <hip/hip_bf16.h>

// CapsModel: B=64 N=32 H=W=16 A=16 K=3 stride=2 -> Ho=Wo=7, M=32, SD=4, D=16
// conv routing: 2 sites/block, 512 thr, ONE site per thread (tid>>8), f16 dot2
//   votes. R10 design point kept (VGPR<=64 via (512,4), no spills, 32 KB LDS).
//   R11: s_v rows padded to 20 floats (16B-aligned) so vc is read as 4x
//   ds_read_b128 per body instead of 16x ds_read_b32 (the 17-pad forced
//   scalar reads); transposes fused into one launch.
// fc routing: pass-split kernels (unchanged).

#define LN_EPS 1e-5f

typedef _Float16 h2 __attribute__((ext_vector_type(2)));

__device__ __forceinline__ unsigned packh2(float a, float b) {
    const unsigned short ua = __builtin_bit_cast(unsigned short, (_Float16)a);
    const unsigned short ub = __builtin_bit_cast(unsigned short, (_Float16)b);
    return (unsigned)ua | ((unsigned)ub << 16);
}

__device__ __forceinline__ float fdot2u(unsigned a, unsigned b, float c) {
#if __has_builtin(__builtin_amdgcn_fdot2)
    return __builtin_amdgcn_fdot2(__builtin_bit_cast(h2, a),
                                  __builtin_bit_cast(h2, b), c, false);
#else
    const h2 ha = __builtin_bit_cast(h2, a), hb = __builtin_bit_cast(h2, b);
    return fmaf((float)ha.x, (float)hb.x, fmaf((float)ha.y, (float)hb.y, c));
#endif
}

// ---------------- fused weight transposes ----------------
// wTh [288][32][4(d)][4(x)] f16: row r = n*9+kl (n-major, matches s_inp).
// wT2b [1568][16][16] fp32: [n][m (pad 10->16, zeros)][x*4+d]
__global__ __launch_bounds__(256) void transpose_weights(
    const float* __restrict__ wconv, const float* __restrict__ wfc,
    unsigned short* __restrict__ wTh, float* __restrict__ wT2b)
{
    const int blk = blockIdx.x;
    if (blk < 576) {
        const int i = blk * 256 + threadIdx.x;
        if (i < 147456) {
            const int x = i & 3, d = (i >> 2) & 3, mm = (i >> 4) & 31, r = i >> 9;
            const int n = r / 9, kl = r % 9;
            const float v = wconv[((kl * 32 + n) * 16 + x * 4 + d) * 32 + mm];
            wTh[i] = __builtin_bit_cast(unsigned short, (_Float16)v);
        }
    } else {
        const int j = (blk - 576) * 256 + threadIdx.x;
        if (j < 401408) {
            const int xd = j & 15, mm = (j >> 4) & 15, n = j >> 8;
            const int x = xd >> 2, dd = xd & 3;
            wT2b[j] = (mm < 10) ? wfc[((n * 4 + x) * 4 + dd) * 10 + mm] : 0.f;
        }
    }
}

// split variants (fallback layout when ws is tight: wT2b aliases wTh and
// must be written AFTER conv consumed wTh)
__global__ __launch_bounds__(256) void transpose_wconv(
    const float* __restrict__ wconv, unsigned short* __restrict__ wTh)
{
    const int i = blockIdx.x * 256 + threadIdx.x;
    if (i < 147456) {
        const int x = i & 3, d = (i >> 2) & 3, mm = (i >> 4) & 31, r = i >> 9;
        const int n = r / 9, kl = r % 9;
        const float v = wconv[((kl * 32 + n) * 16 + x * 4 + d) * 32 + mm];
        wTh[i] = __builtin_bit_cast(unsigned short, (_Float16)v);
    }
}
__global__ __launch_bounds__(256) void transpose_wfc(
    const float* __restrict__ wfc, float* __restrict__ wT2b)
{
    const int j = blockIdx.x * 256 + threadIdx.x;
    if (j < 401408) {
        const int xd = j & 15, mm = (j >> 4) & 15, n = j >> 8;
        const int x = xd >> 2, dd = xd & 3;
        wT2b[j] = (mm < 10) ? wfc[((n * 4 + x) * 4 + dd) * 10 + mm] : 0.f;
    }
}

// ---------------- Stage 1: conv routing ----------------
__global__ __launch_bounds__(512, 4) void conv_routing_kernel(
    const float* __restrict__ x,             // [64][32][16][16][16]
    const unsigned short* __restrict__ wTh,  // [288][32][16] f16 [d][x]
    const float* __restrict__ ln1g,
    const float* __restrict__ ln1b,
    const int*   __restrict__ nroute,
    float* __restrict__ vout)                // [64][32][49][16]
{
    __shared__ unsigned short s_inp[2][288][16];  // f16 (a*4+x order), 18,432 B
    __shared__ float s_v[2][32][20];              // 5,120 B (20-pad: 16B-aligned rows)
    __shared__ float s_red[2][2][32][17];         // 8,704 B

    const int tid    = threadIdx.x;
    const int site_l = tid >> 8;        // 0/1 : this thread's site
    const int m      = tid & 31;
    const int g      = (tid >> 5) & 7;  // 0..7 within site
    const int lw     = (tid >> 6) & 3;  // wave index within site
    const int site0  = blockIdx.x * 2;

    // stage inp (coalesced float4 loads, f16 pack)
    for (int i = tid; i < 2304; i += 512) {     // 2 sites * 288 rows * 4 quads
        const int s = (i >= 1152) ? 1 : 0;
        const int j = s ? i - 1152 : i;
        const int row = j >> 2, q = j & 3;
        const int site = site0 + s;
        const int b = site / 49, hw = site % 49;
        const int h = hw / 7, w = hw % 7;
        const int n = row / 9, kl = row % 9;
        const int k = kl / 3, l = kl % 3;
        const float4 val = *(const float4*)(
            x + ((((b * 32 + n) * 16 + (2 * h + k)) * 16 + (2 * w + l)) * 16 + q * 4));
        uint2 p;
        p.x = packh2(val.x, val.y);
        p.y = packh2(val.z, val.w);
        *(uint2*)(&s_inp[s][row][q * 4]) = p;
    }
    __syncthreads();

    const int R = *nroute;
    const int nkl0 = g * 36;
    const unsigned short* const wp0 = wTh + (nkl0 * 32 + m) * 16;

    for (int pass = 0; pass < R; ++pass) {
        float vn[16];
#pragma unroll
        for (int i = 0; i < 16; ++i) vn[i] = 0.f;
        const int routing = (pass != 0);

        const unsigned short* wp = wp0;
        for (int t = 0; t < 36; ++t, wp += 512) {
            // w fragment: 8 packed f16 pairs ([d][x-pair])
            uint4 wa = *(const uint4*)(wp);
            uint4 wb = *(const uint4*)(wp + 8);
            const unsigned wu[8] = { wa.x, wa.y, wa.z, wa.w, wb.x, wb.y, wb.z, wb.w };
            // input row: 8 packed f16 pairs ([a][x-pair])
            const uint4* rp = (const uint4*)(&s_inp[site_l][nkl0 + t][0]);
            const uint4 ua = rp[0], ub = rp[1];
            const unsigned iu[8] = { ua.x, ua.y, ua.z, ua.w, ub.x, ub.y, ub.z, ub.w };

            if (!routing) {
#pragma unroll
                for (int a = 0; a < 4; ++a) {
#pragma unroll
                    for (int d = 0; d < 4; ++d) {
                        vn[a * 4 + d] = fdot2u(iu[a * 2], wu[d * 2],
                            fdot2u(iu[a * 2 + 1], wu[d * 2 + 1], vn[a * 4 + d]));
                    }
                }
            } else {
                float uh[16];
#pragma unroll
                for (int a = 0; a < 4; ++a) {
#pragma unroll
                    for (int d = 0; d < 4; ++d) {
                        uh[a * 4 + d] = fdot2u(iu[a * 2], wu[d * 2],
                            fdot2u(iu[a * 2 + 1], wu[d * 2 + 1], 0.f));
                    }
                }
                // vc via 4x ds_read_b128 (rows 16B-aligned with 20-pad)
                const float4* vc4 = (const float4*)(&s_v[site_l][m][0]);
                const float4 c0 = vc4[0], c1 = vc4[1], c2 = vc4[2], c3 = vc4[3];
                float l0 = uh[0] * c0.x, l1 = uh[1] * c0.y;
                float l2 = uh[2] * c0.z, l3 = uh[3] * c0.w;
                l0 = fmaf(uh[4], c1.x, l0);  l1 = fmaf(uh[5], c1.y, l1);
                l2 = fmaf(uh[6], c1.z, l2);  l3 = fmaf(uh[7], c1.w, l3);
                l0 = fmaf(uh[8], c2.x, l0);  l1 = fmaf(uh[9], c2.y, l1);
                l2 = fmaf(uh[10], c2.z, l2); l3 = fmaf(uh[11], c2.w, l3);
                l0 = fmaf(uh[12], c3.x, l0); l1 = fmaf(uh[13], c3.y, l1);
                l2 = fmaf(uh[14], c3.z, l2); l3 = fmaf(uh[15], c3.w, l3);
                const float lg = ((l0 + l1) + (l2 + l3)) * 0.25f;
                const float e = __expf(lg);
                float sm = e;
#pragma unroll
                for (int off = 16; off >= 1; off >>= 1)
                    sm += __shfl_xor(sm, off, 32);
                const float qk = e * __builtin_amdgcn_rcpf(sm * (1.f + 1e-10f));
#pragma unroll
                for (int i = 0; i < 16; ++i) vn[i] = fmaf(qk, uh[i], vn[i]);
            }
        }

        // combine the 2 g's within this wave (both halves end with pair-sum)
#pragma unroll
        for (int i = 0; i < 16; ++i) vn[i] += __shfl_xor(vn[i], 32, 64);

        // 2-stage tree over the 4 waves of this site
        if (lw >= 2) {
#pragma unroll
            for (int i = 0; i < 16; ++i) s_red[lw - 2][site_l][m][i] = vn[i];
        }
        __syncthreads();
        if (lw < 2) {
#pragma unroll
            for (int i = 0; i < 16; ++i) vn[i] += s_red[lw][site_l][m][i];
            if (lw == 1) {
#pragma unroll
                for (int i = 0; i < 16; ++i) s_red[1][site_l][m][i] = vn[i];
            }
        }
        __syncthreads();
        if (lw == 0) {
#pragma unroll
            for (int i = 0; i < 16; ++i) vn[i] += s_red[1][site_l][m][i];
            const float scale = pass ? 1.f : (1.f / 32.f);
            float mu = 0.f;
#pragma unroll
            for (int i = 0; i < 16; ++i) { vn[i] *= scale; mu += vn[i]; }
            mu *= (1.f / 16.f);
            float var = 0.f;
#pragma unroll
            for (int i = 0; i < 16; ++i) {
                const float d0 = vn[i] - mu;
                var = fmaf(d0, d0, var);
            }
            var *= (1.f / 16.f);
            const float inv = rsqrtf(var + LN_EPS);
#pragma unroll
            for (int i = 0; i < 16; ++i)
                s_v[site_l][m][i] = (vn[i] - mu) * inv * ln1g[i] + ln1b[i];
        }
        __syncthreads();
    }

    // write v (scalar, coalesced in 16-elem runs)
    for (int p = tid; p < 1024; p += 512) {
        const int s = p >> 9, mm = (p >> 4) & 31, i = p & 15;
        const int site = site0 + s;
        const int b = site / 49, hw = site % 49;
        vout[((b * 32 + mm) * 49 + hw) * 16 + i] = s_v[s][mm][i];
    }
}

// ---------------- Stage 2: FC routing (pass-split, unchanged) ----------------
__global__ __launch_bounds__(256, 4) void fc_partial(
    const float* __restrict__ fcin,  // [64][1568][16]
    const float* __restrict__ wT2b,  // [1568][16][16] ([n][ml][x*4+d])
    const float* __restrict__ u,     // [64][16][16]
    const int*   __restrict__ nroute,
    const int    pass,
    float* __restrict__ partial)     // [512][16][16]
{
    __shared__ float s_red[4][16][17];

    const int R = *nroute;
    if (pass >= R) return;
    const int blk = blockIdx.x;
    const int b = blk >> 3, c = blk & 7;
    const int tid = threadIdx.x;
    const int ml = tid & 15, grp = tid >> 4;
    const int wv = tid >> 6;
    const float* fb = fcin + (b * 1568 + c * 196) * 16;
    const float* wb = wT2b + (c * 196 * 16) * 16;

    float un[16];
#pragma unroll
    for (int i = 0; i < 16; ++i) un[i] = 0.f;
    float ur[16];
    if (pass) {
#pragma unroll
        for (int q = 0; q < 4; ++q)
            *(float4*)(&ur[q * 4]) = *(const float4*)(u + (b * 16 + ml) * 16 + q * 4);
    }

    for (int t = 0; t < 13; ++t) {
        const int off = t * 16 + grp;
        if (off >= 196) break;
        float iv[16], wv_[16];
        const float* ip = fb + off * 16;
        const float* wp = wb + (off * 16 + ml) * 16;
#pragma unroll
        for (int q = 0; q < 4; ++q) {
            *(float4*)(&iv[q * 4]) = *(const float4*)(ip + q * 4);
            *(float4*)(&wv_[q * 4]) = *(const float4*)(wp + q * 4);
        }
        float vote[16];
#pragma unroll
        for (int a = 0; a < 4; ++a) {
#pragma unroll
            for (int d = 0; d < 4; ++d) {
                float acc = iv[a * 4 + 0] * wv_[0 + d];
                acc = fmaf(iv[a * 4 + 1], wv_[4 + d], acc);
                acc = fmaf(iv[a * 4 + 2], wv_[8 + d], acc);
                acc = fmaf(iv[a * 4 + 3], wv_[12 + d], acc);
                vote[a * 4 + d] = acc;
            }
        }
        if (pass == 0) {
#pragma unroll
            for (int i = 0; i < 16; ++i) un[i] += vote[i];
        } else {
            float l0 = vote[0] * ur[0], l1 = vote[1] * ur[1];
            float l2 = vote[2] * ur[2], l3 = vote[3] * ur[3];
#pragma unroll
            for (int i = 4; i < 16; i += 4) {
                l0 = fmaf(vote[i + 0], ur[i + 0], l0);
                l1 = fmaf(vote[i + 1], ur[i + 1], l1);
                l2 = fmaf(vote[i + 2], ur[i + 2], l2);
                l3 = fmaf(vote[i + 3], ur[i + 3], l3);
            }
            const float lg = ((l0 + l1) + (l2 + l3)) * 0.25f;
            float e = __expf(lg);
            if (ml >= 10) e = 0.f;
            float sm = e;
#pragma unroll
            for (int off2 = 8; off2 >= 1; off2 >>= 1)
                sm += __shfl_xor(sm, off2, 16);
            const float qk = e * __builtin_amdgcn_rcpf(sm * (1.f + 1e-10f));
#pragma unroll
            for (int i = 0; i < 16; ++i) un[i] = fmaf(qk, vote[i], un[i]);
        }
    }

#pragma unroll
    for (int i = 0; i < 16; ++i) {
        un[i] += __shfl_xor(un[i], 16, 64);
        un[i] += __shfl_xor(un[i], 32, 64);
    }
    if ((tid & 63) < 16) {
#pragma unroll
        for (int i = 0; i < 16; ++i) s_red[wv][ml][i] = un[i];
    }
    __syncthreads();
    {
        const int mlf = tid >> 4, i = tid & 15;
        const float s = s_red[0][mlf][i] + s_red[1][mlf][i]
                      + s_red[2][mlf][i] + s_red[3][mlf][i];
        partial[(blk * 16 + mlf) * 16 + i] = s;
    }
}

__global__ __launch_bounds__(256) void fc_combine(
    const float* __restrict__ partial,  // [512][16][16]
    const float* __restrict__ ln2g,
    const float* __restrict__ ln2b,
    const int*   __restrict__ nroute,
    const int    pass,
    float* __restrict__ u,              // [64][16][16]
    float* __restrict__ out)            // [64][10][16]
{
    const int R = *nroute;
    if (pass >= R) return;
    const int b = blockIdx.x;
    const int tid = threadIdx.x;
    const int i = tid & 15, ml = tid >> 4;

    float s = 0.f;
#pragma unroll
    for (int c = 0; c < 8; ++c)
        s += partial[((b * 8 + c) * 16 + ml) * 16 + i];
    if (pass == 0) s *= 0.1f;

    float mu = s;
#pragma unroll
    for (int off = 8; off >= 1; off >>= 1) mu += __shfl_xor(mu, off, 16);
    mu *= (1.f / 16.f);
    const float d0 = s - mu;
    float var = d0 * d0;
#pragma unroll
    for (int off = 8; off >= 1; off >>= 1) var += __shfl_xor(var, off, 16);
    var *= (1.f / 16.f);
    const float r = (s - mu) * rsqrtf(var + LN_EPS) * ln2g[i] + ln2b[i];

    u[(b * 16 + ml) * 16 + i] = r;
    if (pass == R - 1 && ml < 10) out[(b * 10 + ml) * 16 + i] = r;
}

extern "C" void kernel_launch(void* const* d_in, const int* in_sizes, int n_in,
                              void* d_out, int out_size, void* d_ws, size_t ws_size,
                              hipStream_t stream) {
    const float* x     = (const float*)d_in[0];
    const float* wconv = (const float*)d_in[1];
    const float* wfc   = (const float*)d_in[2];
    const float* ln1g  = (const float*)d_in[3];
    const float* ln1b  = (const float*)d_in[4];
    const float* ln2g  = (const float*)d_in[5];
    const float* ln2b  = (const float*)d_in[6];
    const int*   nrt   = (const int*)d_in[7];
    float* out = (float*)d_out;

    float* vout = (float*)d_ws;                                  // 6,422,528 B
    unsigned short* wTh = (unsigned short*)((char*)d_ws + 6422528);  // 294,912 B

    if (ws_size >= 8912896) {
        // roomy layout: wT2b separate -> single fused transpose up front
        float* wT2b    = (float*)((char*)d_ws + 6717440);        // 1,605,632 B
        float* ubuf    = (float*)((char*)d_ws + 8323072);        // 65,536 B
        float* partial = (float*)((char*)d_ws + 8388608);        // 524,288 B

        hipLaunchKernelGGL(transpose_weights, dim3(2144), dim3(256), 0, stream,
                           wconv, wfc, wTh, wT2b);
        hipLaunchKernelGGL(conv_routing_kernel, dim3(1568), dim3(512), 0, stream,
                           x, wTh, ln1g, ln1b, nrt, vout);
        for (int pass = 0; pass < 3; ++pass) {
            hipLaunchKernelGGL(fc_partial, dim3(512), dim3(256), 0, stream,
                               vout, wT2b, ubuf, nrt, pass, partial);
            hipLaunchKernelGGL(fc_combine, dim3(64), dim3(256), 0, stream,
                               partial, ln2g, ln2b, nrt, pass, ubuf, out);
        }
    } else {
        // tight layout (R10): wT2b aliases wTh, sequenced after conv
        float* wT2b    = (float*)((char*)d_ws + 6422528);
        float* ubuf    = (float*)((char*)d_ws + 8028160);        // 65,536 B
        float* partial = (float*)((char*)d_ws + 8093696);        // 524,288 B

        hipLaunchKernelGGL(transpose_wconv, dim3(576), dim3(256), 0, stream,
                           wconv, wTh);
        hipLaunchKernelGGL(conv_routing_kernel, dim3(1568), dim3(512), 0, stream,
                           x, wTh, ln1g, ln1b, nrt, vout);
        hipLaunchKernelGGL(transpose_wfc, dim3(1568), dim3(256), 0, stream,
                           wfc, wT2b);
        for (int pass = 0; pass < 3; ++pass) {
            hipLaunchKernelGGL(fc_partial, dim3(512), dim3(256), 0, stream,
                               vout, wT2b, ubuf, nrt, pass, partial);
            hipLaunchKernelGGL(fc_combine, dim3(64), dim3(256), 0, stream,
                               partial, ln2g, ln2b, nrt, pass, ubuf, out);
        }
    }
}

// Round 12
// 398.534 us; speedup vs baseline: 1.0591x; 1.0591x over previous
//
#include <hip/hip_runtime.h>
#include <hip/hip_bf16.h>

// CapsModel: B=64 N=32 H=W=16 A=16 K=3 stride=2 -> Ho=Wo=7, M=32, SD=4, D=16
// conv routing: 2 sites/block, 512 thr, ONE site per thread (tid>>8), f16 dot2
//   votes. R10 design point (VGPR<=64 via (512,4), no spills, 31.7 KB LDS,
//   17-pad s_v). R12: vc hoisted to registers ONCE PER PASS (R10 re-read it
//   from LDS every body: 16 ds_read_b32 x 36 t -> DS pipe was the bottleneck
//   at ~245 us/CU; now 36x fewer vc reads).
// fc routing: pass-split kernels (unchanged).

#define LN_EPS 1e-5f

typedef _Float16 h2 __attribute__((ext_vector_type(2)));

__device__ __forceinline__ unsigned packh2(float a, float b) {
    const unsigned short ua = __builtin_bit_cast(unsigned short, (_Float16)a);
    const unsigned short ub = __builtin_bit_cast(unsigned short, (_Float16)b);
    return (unsigned)ua | ((unsigned)ub << 16);
}

__device__ __forceinline__ float fdot2u(unsigned a, unsigned b, float c) {
#if __has_builtin(__builtin_amdgcn_fdot2)
    return __builtin_amdgcn_fdot2(__builtin_bit_cast(h2, a),
                                  __builtin_bit_cast(h2, b), c, false);
#else
    const h2 ha = __builtin_bit_cast(h2, a), hb = __builtin_bit_cast(h2, b);
    return fmaf((float)ha.x, (float)hb.x, fmaf((float)ha.y, (float)hb.y, c));
#endif
}

// ---------------- fused weight transposes ----------------
// wTh [288][32][4(d)][4(x)] f16: row r = n*9+kl (n-major, matches s_inp).
// wT2b [1568][16][16] fp32: [n][m (pad 10->16, zeros)][x*4+d]
__global__ __launch_bounds__(256) void transpose_weights(
    const float* __restrict__ wconv, const float* __restrict__ wfc,
    unsigned short* __restrict__ wTh, float* __restrict__ wT2b)
{
    const int blk = blockIdx.x;
    if (blk < 576) {
        const int i = blk * 256 + threadIdx.x;
        if (i < 147456) {
            const int x = i & 3, d = (i >> 2) & 3, mm = (i >> 4) & 31, r = i >> 9;
            const int n = r / 9, kl = r % 9;
            const float v = wconv[((kl * 32 + n) * 16 + x * 4 + d) * 32 + mm];
            wTh[i] = __builtin_bit_cast(unsigned short, (_Float16)v);
        }
    } else {
        const int j = (blk - 576) * 256 + threadIdx.x;
        if (j < 401408) {
            const int xd = j & 15, mm = (j >> 4) & 15, n = j >> 8;
            const int x = xd >> 2, dd = xd & 3;
            wT2b[j] = (mm < 10) ? wfc[((n * 4 + x) * 4 + dd) * 10 + mm] : 0.f;
        }
    }
}

// split variants (fallback when ws is tight: wT2b aliases wTh, sequenced)
__global__ __launch_bounds__(256) void transpose_wconv(
    const float* __restrict__ wconv, unsigned short* __restrict__ wTh)
{
    const int i = blockIdx.x * 256 + threadIdx.x;
    if (i < 147456) {
        const int x = i & 3, d = (i >> 2) & 3, mm = (i >> 4) & 31, r = i >> 9;
        const int n = r / 9, kl = r % 9;
        const float v = wconv[((kl * 32 + n) * 16 + x * 4 + d) * 32 + mm];
        wTh[i] = __builtin_bit_cast(unsigned short, (_Float16)v);
    }
}
__global__ __launch_bounds__(256) void transpose_wfc(
    const float* __restrict__ wfc, float* __restrict__ wT2b)
{
    const int j = blockIdx.x * 256 + threadIdx.x;
    if (j < 401408) {
        const int xd = j & 15, mm = (j >> 4) & 15, n = j >> 8;
        const int x = xd >> 2, dd = xd & 3;
        wT2b[j] = (mm < 10) ? wfc[((n * 4 + x) * 4 + dd) * 10 + mm] : 0.f;
    }
}

// ---------------- Stage 1: conv routing ----------------
__global__ __launch_bounds__(512, 4) void conv_routing_kernel(
    const float* __restrict__ x,             // [64][32][16][16][16]
    const unsigned short* __restrict__ wTh,  // [288][32][16] f16 [d][x]
    const float* __restrict__ ln1g,
    const float* __restrict__ ln1b,
    const int*   __restrict__ nroute,
    float* __restrict__ vout)                // [64][32][49][16]
{
    __shared__ unsigned short s_inp[2][288][16];  // f16 (a*4+x order), 18,432 B
    __shared__ float s_v[2][32][17];              // 4,352 B (17-pad)
    __shared__ float s_red[2][2][32][17];         // 8,704 B

    const int tid    = threadIdx.x;
    const int site_l = tid >> 8;        // 0/1 : this thread's site
    const int m      = tid & 31;
    const int g      = (tid >> 5) & 7;  // 0..7 within site
    const int lw     = (tid >> 6) & 3;  // wave index within site
    const int site0  = blockIdx.x * 2;

    // stage inp (coalesced float4 loads, f16 pack)
    for (int i = tid; i < 2304; i += 512) {     // 2 sites * 288 rows * 4 quads
        const int s = (i >= 1152) ? 1 : 0;
        const int j = s ? i - 1152 : i;
        const int row = j >> 2, q = j & 3;
        const int site = site0 + s;
        const int b = site / 49, hw = site % 49;
        const int h = hw / 7, w = hw % 7;
        const int n = row / 9, kl = row % 9;
        const int k = kl / 3, l = kl % 3;
        const float4 val = *(const float4*)(
            x + ((((b * 32 + n) * 16 + (2 * h + k)) * 16 + (2 * w + l)) * 16 + q * 4));
        uint2 p;
        p.x = packh2(val.x, val.y);
        p.y = packh2(val.z, val.w);
        *(uint2*)(&s_inp[s][row][q * 4]) = p;
    }
    __syncthreads();

    const int R = *nroute;
    const int nkl0 = g * 36;
    const unsigned short* const wp0 = wTh + (nkl0 * 32 + m) * 16;

    for (int pass = 0; pass < R; ++pass) {
        float vn[16];
#pragma unroll
        for (int i = 0; i < 16; ++i) vn[i] = 0.f;
        const int routing = (pass != 0);

        // hoist vc into registers once per pass (R10 re-read per body)
        float vc[16];
        if (routing) {
#pragma unroll
            for (int i = 0; i < 16; ++i) vc[i] = s_v[site_l][m][i];
        }

        const unsigned short* wp = wp0;
        for (int t = 0; t < 36; ++t, wp += 512) {
            // w fragment: 8 packed f16 pairs ([d][x-pair])
            uint4 wa = *(const uint4*)(wp);
            uint4 wb = *(const uint4*)(wp + 8);
            const unsigned wu[8] = { wa.x, wa.y, wa.z, wa.w, wb.x, wb.y, wb.z, wb.w };
            // input row: 8 packed f16 pairs ([a][x-pair])
            const uint4* rp = (const uint4*)(&s_inp[site_l][nkl0 + t][0]);
            const uint4 ua = rp[0], ub = rp[1];
            const unsigned iu[8] = { ua.x, ua.y, ua.z, ua.w, ub.x, ub.y, ub.z, ub.w };

            if (!routing) {
#pragma unroll
                for (int a = 0; a < 4; ++a) {
#pragma unroll
                    for (int d = 0; d < 4; ++d) {
                        vn[a * 4 + d] = fdot2u(iu[a * 2], wu[d * 2],
                            fdot2u(iu[a * 2 + 1], wu[d * 2 + 1], vn[a * 4 + d]));
                    }
                }
            } else {
                float uh[16];
#pragma unroll
                for (int a = 0; a < 4; ++a) {
#pragma unroll
                    for (int d = 0; d < 4; ++d) {
                        uh[a * 4 + d] = fdot2u(iu[a * 2], wu[d * 2],
                            fdot2u(iu[a * 2 + 1], wu[d * 2 + 1], 0.f));
                    }
                }
                float l0 = uh[0] * vc[0], l1 = uh[1] * vc[1];
                float l2 = uh[2] * vc[2], l3 = uh[3] * vc[3];
#pragma unroll
                for (int i = 4; i < 16; i += 4) {
                    l0 = fmaf(uh[i + 0], vc[i + 0], l0);
                    l1 = fmaf(uh[i + 1], vc[i + 1], l1);
                    l2 = fmaf(uh[i + 2], vc[i + 2], l2);
                    l3 = fmaf(uh[i + 3], vc[i + 3], l3);
                }
                const float lg = ((l0 + l1) + (l2 + l3)) * 0.25f;
                const float e = __expf(lg);
                float sm = e;
#pragma unroll
                for (int off = 16; off >= 1; off >>= 1)
                    sm += __shfl_xor(sm, off, 32);
                const float qk = e * __builtin_amdgcn_rcpf(sm * (1.f + 1e-10f));
#pragma unroll
                for (int i = 0; i < 16; ++i) vn[i] = fmaf(qk, uh[i], vn[i]);
            }
        }

        // combine the 2 g's within this wave (both halves end with pair-sum)
#pragma unroll
        for (int i = 0; i < 16; ++i) vn[i] += __shfl_xor(vn[i], 32, 64);

        // 2-stage tree over the 4 waves of this site
        if (lw >= 2) {
#pragma unroll
            for (int i = 0; i < 16; ++i) s_red[lw - 2][site_l][m][i] = vn[i];
        }
        __syncthreads();
        if (lw < 2) {
#pragma unroll
            for (int i = 0; i < 16; ++i) vn[i] += s_red[lw][site_l][m][i];
            if (lw == 1) {
#pragma unroll
                for (int i = 0; i < 16; ++i) s_red[1][site_l][m][i] = vn[i];
            }
        }
        __syncthreads();
        if (lw == 0) {
#pragma unroll
            for (int i = 0; i < 16; ++i) vn[i] += s_red[1][site_l][m][i];
            const float scale = pass ? 1.f : (1.f / 32.f);
            float mu = 0.f;
#pragma unroll
            for (int i = 0; i < 16; ++i) { vn[i] *= scale; mu += vn[i]; }
            mu *= (1.f / 16.f);
            float var = 0.f;
#pragma unroll
            for (int i = 0; i < 16; ++i) {
                const float d0 = vn[i] - mu;
                var = fmaf(d0, d0, var);
            }
            var *= (1.f / 16.f);
            const float inv = rsqrtf(var + LN_EPS);
#pragma unroll
            for (int i = 0; i < 16; ++i)
                s_v[site_l][m][i] = (vn[i] - mu) * inv * ln1g[i] + ln1b[i];
        }
        __syncthreads();
    }

    // write v (scalar, coalesced in 16-elem runs)
    for (int p = tid; p < 1024; p += 512) {
        const int s = p >> 9, mm = (p >> 4) & 31, i = p & 15;
        const int site = site0 + s;
        const int b = site / 49, hw = site % 49;
        vout[((b * 32 + mm) * 49 + hw) * 16 + i] = s_v[s][mm][i];
    }
}

// ---------------- Stage 2: FC routing (pass-split, unchanged) ----------------
__global__ __launch_bounds__(256, 4) void fc_partial(
    const float* __restrict__ fcin,  // [64][1568][16]
    const float* __restrict__ wT2b,  // [1568][16][16] ([n][ml][x*4+d])
    const float* __restrict__ u,     // [64][16][16]
    const int*   __restrict__ nroute,
    const int    pass,
    float* __restrict__ partial)     // [512][16][16]
{
    __shared__ float s_red[4][16][17];

    const int R = *nroute;
    if (pass >= R) return;
    const int blk = blockIdx.x;
    const int b = blk >> 3, c = blk & 7;
    const int tid = threadIdx.x;
    const int ml = tid & 15, grp = tid >> 4;
    const int wv = tid >> 6;
    const float* fb = fcin + (b * 1568 + c * 196) * 16;
    const float* wb = wT2b + (c * 196 * 16) * 16;

    float un[16];
#pragma unroll
    for (int i = 0; i < 16; ++i) un[i] = 0.f;
    float ur[16];
    if (pass) {
#pragma unroll
        for (int q = 0; q < 4; ++q)
            *(float4*)(&ur[q * 4]) = *(const float4*)(u + (b * 16 + ml) * 16 + q * 4);
    }

    for (int t = 0; t < 13; ++t) {
        const int off = t * 16 + grp;
        if (off >= 196) break;
        float iv[16], wv_[16];
        const float* ip = fb + off * 16;
        const float* wp = wb + (off * 16 + ml) * 16;
#pragma unroll
        for (int q = 0; q < 4; ++q) {
            *(float4*)(&iv[q * 4]) = *(const float4*)(ip + q * 4);
            *(float4*)(&wv_[q * 4]) = *(const float4*)(wp + q * 4);
        }
        float vote[16];
#pragma unroll
        for (int a = 0; a < 4; ++a) {
#pragma unroll
            for (int d = 0; d < 4; ++d) {
                float acc = iv[a * 4 + 0] * wv_[0 + d];
                acc = fmaf(iv[a * 4 + 1], wv_[4 + d], acc);
                acc = fmaf(iv[a * 4 + 2], wv_[8 + d], acc);
                acc = fmaf(iv[a * 4 + 3], wv_[12 + d], acc);
                vote[a * 4 + d] = acc;
            }
        }
        if (pass == 0) {
#pragma unroll
            for (int i = 0; i < 16; ++i) un[i] += vote[i];
        } else {
            float l0 = vote[0] * ur[0], l1 = vote[1] * ur[1];
            float l2 = vote[2] * ur[2], l3 = vote[3] * ur[3];
#pragma unroll
            for (int i = 4; i < 16; i += 4) {
                l0 = fmaf(vote[i + 0], ur[i + 0], l0);
                l1 = fmaf(vote[i + 1], ur[i + 1], l1);
                l2 = fmaf(vote[i + 2], ur[i + 2], l2);
                l3 = fmaf(vote[i + 3], ur[i + 3], l3);
            }
            const float lg = ((l0 + l1) + (l2 + l3)) * 0.25f;
            float e = __expf(lg);
            if (ml >= 10) e = 0.f;
            float sm = e;
#pragma unroll
            for (int off2 = 8; off2 >= 1; off2 >>= 1)
                sm += __shfl_xor(sm, off2, 16);
            const float qk = e * __builtin_amdgcn_rcpf(sm * (1.f + 1e-10f));
#pragma unroll
            for (int i = 0; i < 16; ++i) un[i] = fmaf(qk, vote[i], un[i]);
        }
    }

#pragma unroll
    for (int i = 0; i < 16; ++i) {
        un[i] += __shfl_xor(un[i], 16, 64);
        un[i] += __shfl_xor(un[i], 32, 64);
    }
    if ((tid & 63) < 16) {
#pragma unroll
        for (int i = 0; i < 16; ++i) s_red[wv][ml][i] = un[i];
    }
    __syncthreads();
    {
        const int mlf = tid >> 4, i = tid & 15;
        const float s = s_red[0][mlf][i] + s_red[1][mlf][i]
                      + s_red[2][mlf][i] + s_red[3][mlf][i];
        partial[(blk * 16 + mlf) * 16 + i] = s;
    }
}

__global__ __launch_bounds__(256) void fc_combine(
    const float* __restrict__ partial,  // [512][16][16]
    const float* __restrict__ ln2g,
    const float* __restrict__ ln2b,
    const int*   __restrict__ nroute,
    const int    pass,
    float* __restrict__ u,              // [64][16][16]
    float* __restrict__ out)            // [64][10][16]
{
    const int R = *nroute;
    if (pass >= R) return;
    const int b = blockIdx.x;
    const int tid = threadIdx.x;
    const int i = tid & 15, ml = tid >> 4;

    float s = 0.f;
#pragma unroll
    for (int c = 0; c < 8; ++c)
        s += partial[((b * 8 + c) * 16 + ml) * 16 + i];
    if (pass == 0) s *= 0.1f;

    float mu = s;
#pragma unroll
    for (int off = 8; off >= 1; off >>= 1) mu += __shfl_xor(mu, off, 16);
    mu *= (1.f / 16.f);
    const float d0 = s - mu;
    float var = d0 * d0;
#pragma unroll
    for (int off = 8; off >= 1; off >>= 1) var += __shfl_xor(var, off, 16);
    var *= (1.f / 16.f);
    const float r = (s - mu) * rsqrtf(var + LN_EPS) * ln2g[i] + ln2b[i];

    u[(b * 16 + ml) * 16 + i] = r;
    if (pass == R - 1 && ml < 10) out[(b * 10 + ml) * 16 + i] = r;
}

extern "C" void kernel_launch(void* const* d_in, const int* in_sizes, int n_in,
                              void* d_out, int out_size, void* d_ws, size_t ws_size,
                              hipStream_t stream) {
    const float* x     = (const float*)d_in[0];
    const float* wconv = (const float*)d_in[1];
    const float* wfc   = (const float*)d_in[2];
    const float* ln1g  = (const float*)d_in[3];
    const float* ln1b  = (const float*)d_in[4];
    const float* ln2g  = (const float*)d_in[5];
    const float* ln2b  = (const float*)d_in[6];
    const int*   nrt   = (const int*)d_in[7];
    float* out = (float*)d_out;

    float* vout = (float*)d_ws;                                  // 6,422,528 B
    unsigned short* wTh = (unsigned short*)((char*)d_ws + 6422528);  // 294,912 B

    if (ws_size >= 8912896) {
        // roomy layout: wT2b separate -> single fused transpose up front
        float* wT2b    = (float*)((char*)d_ws + 6717440);        // 1,605,632 B
        float* ubuf    = (float*)((char*)d_ws + 8323072);        // 65,536 B
        float* partial = (float*)((char*)d_ws + 8388608);        // 524,288 B

        hipLaunchKernelGGL(transpose_weights, dim3(2144), dim3(256), 0, stream,
                           wconv, wfc, wTh, wT2b);
        hipLaunchKernelGGL(conv_routing_kernel, dim3(1568), dim3(512), 0, stream,
                           x, wTh, ln1g, ln1b, nrt, vout);
        for (int pass = 0; pass < 3; ++pass) {
            hipLaunchKernelGGL(fc_partial, dim3(512), dim3(256), 0, stream,
                               vout, wT2b, ubuf, nrt, pass, partial);
            hipLaunchKernelGGL(fc_combine, dim3(64), dim3(256), 0, stream,
                               partial, ln2g, ln2b, nrt, pass, ubuf, out);
        }
    } else {
        // tight layout: wT2b aliases wTh, sequenced after conv
        float* wT2b    = (float*)((char*)d_ws + 6422528);
        float* ubuf    = (float*)((char*)d_ws + 8028160);        // 65,536 B
        float* partial = (float*)((char*)d_ws + 8093696);        // 524,288 B

        hipLaunchKernelGGL(transpose_wconv, dim3(576), dim3(256), 0, stream,
                           wconv, wTh);
        hipLaunchKernelGGL(conv_routing_kernel, dim3(1568), dim3(512), 0, stream,
                           x, wTh, ln1g, ln1b, nrt, vout);
        hipLaunchKernelGGL(transpose_wfc, dim3(1568), dim3(256), 0, stream,
                           wfc, wT2b);
        for (int pass = 0; pass < 3; ++pass) {
            hipLaunchKernelGGL(fc_partial, dim3(512), dim3(256), 0, stream,
                               vout, wT2b, ubuf, nrt, pass, partial);
            hipLaunchKernelGGL(fc_combine, dim3(64), dim3(256), 0, stream,
                               partial, ln2g, ln2b, nrt, pass, ubuf, out);
        }
    }
}